// Round 9
// baseline (173.963 us; speedup 1.0000x reference)
//
#include <hip/hip_runtime.h>

#define B_ 16
#define N_ 8192
#define D_ 64

__device__ __forceinline__ float elu1(float x) {
    // F.elu(x)+1 == x+1 for x>0, exp(x) otherwise
    return x > 0.0f ? x + 1.0f : __expf(x);
}

// ---------------------------------------------------------------------------
// Pass 1 (v4 = v3 @ C=128): wave-autonomous partial KV, direct broadcast
// loads (no shfl, no main-loop barriers). grid = B_*C blocks, 256 threads
// (4 waves). C=128 -> 2048 blocks -> 8 blocks/CU -> 8 waves/SIMD (VGPR 64,
// LDS 16KB x 8 = 128KB) for latency hiding — round-8 counters showed v3 was
// latency-bound at 29% occupancy (4 blocks/CU).
// ---------------------------------------------------------------------------
__global__ __launch_bounds__(256, 4) void k1_partial(const float* __restrict__ kin,
                                                     const float* __restrict__ vin,
                                                     float* __restrict__ part,
                                                     int C, int R) {
    const int bid = blockIdx.x;
    const int b = bid / C, c = bid % C;
    const int w = threadIdx.x >> 6;       // wave 0..3
    const int lane = threadIdx.x & 63;
    const int dq = lane >> 3;             // owns d in [8dq, 8dq+8)
    const int eq = lane & 7;              // owns e in [8eq, 8eq+8)

    const int rows_per_wave = R >> 2;     // R/4
    const size_t row0 = (size_t)b * N_ + (size_t)c * R + (size_t)w * rows_per_wave;
    const float* kbase = kin + row0 * D_ + 8 * dq;
    const float* vbase = vin + row0 * D_ + 8 * eq;

    float acc[8][8];
#pragma unroll
    for (int i = 0; i < 8; ++i)
#pragma unroll
        for (int jj = 0; jj < 8; ++jj) acc[i][jj] = 0.0f;

    for (int r = 0; r < rows_per_wave; r += 2) {
        // two rows in flight for load ILP
        const float4 ka0 = *(const float4*)(kbase + (size_t)(r + 0) * D_);
        const float4 kb0 = *(const float4*)(kbase + (size_t)(r + 0) * D_ + 4);
        const float4 va0 = *(const float4*)(vbase + (size_t)(r + 0) * D_);
        const float4 vb0 = *(const float4*)(vbase + (size_t)(r + 0) * D_ + 4);
        const float4 ka1 = *(const float4*)(kbase + (size_t)(r + 1) * D_);
        const float4 kb1 = *(const float4*)(kbase + (size_t)(r + 1) * D_ + 4);
        const float4 va1 = *(const float4*)(vbase + (size_t)(r + 1) * D_);
        const float4 vb1 = *(const float4*)(vbase + (size_t)(r + 1) * D_ + 4);

        const float kk0[8] = {elu1(ka0.x), elu1(ka0.y), elu1(ka0.z), elu1(ka0.w),
                              elu1(kb0.x), elu1(kb0.y), elu1(kb0.z), elu1(kb0.w)};
        const float vv0[8] = {va0.x, va0.y, va0.z, va0.w, vb0.x, vb0.y, vb0.z, vb0.w};
#pragma unroll
        for (int i = 0; i < 8; ++i)
#pragma unroll
            for (int jj = 0; jj < 8; ++jj)
                acc[i][jj] = __fmaf_rn(kk0[i], vv0[jj], acc[i][jj]);

        const float kk1[8] = {elu1(ka1.x), elu1(ka1.y), elu1(ka1.z), elu1(ka1.w),
                              elu1(kb1.x), elu1(kb1.y), elu1(kb1.z), elu1(kb1.w)};
        const float vv1[8] = {va1.x, va1.y, va1.z, va1.w, vb1.x, vb1.y, vb1.z, vb1.w};
#pragma unroll
        for (int i = 0; i < 8; ++i)
#pragma unroll
            for (int jj = 0; jj < 8; ++jj)
                acc[i][jj] = __fmaf_rn(kk1[i], vv1[jj], acc[i][jj]);
    }

    // cross-wave reduction in LDS (layout d*64+e); serial over 4 waves
    __shared__ float red[D_ * D_];
    for (int ww = 0; ww < 4; ++ww) {
        if (w == ww) {
#pragma unroll
            for (int i = 0; i < 8; ++i)
#pragma unroll
                for (int jq = 0; jq < 2; ++jq) {
                    float* p = &red[(8 * dq + i) * D_ + 8 * eq + 4 * jq];
                    if (ww == 0) {
                        float4 o = {acc[i][4 * jq + 0], acc[i][4 * jq + 1],
                                    acc[i][4 * jq + 2], acc[i][4 * jq + 3]};
                        *(float4*)p = o;
                    } else {
                        float4 cur = *(const float4*)p;
                        float4 o = {cur.x + acc[i][4 * jq + 0], cur.y + acc[i][4 * jq + 1],
                                    cur.z + acc[i][4 * jq + 2], cur.w + acc[i][4 * jq + 3]};
                        *(float4*)p = o;
                    }
                }
        }
        __syncthreads();
    }

    float4* pb = (float4*)(part + (size_t)bid * (D_ * D_));
    const float4* rp = (const float4*)red;
#pragma unroll
    for (int u = 0; u < 4; ++u)
        pb[threadIdx.x + 256 * u] = rp[threadIdx.x + 256 * u];
}

// ---------------------------------------------------------------------------
// Atomic fallback (only if ws too small for partials): needs ws pre-zeroed.
// ---------------------------------------------------------------------------
template <int TI>
__global__ __launch_bounds__(256) void k1_atomic(const float* __restrict__ kin,
                                                 const float* __restrict__ vin,
                                                 float* __restrict__ kv,
                                                 int C, int R) {
    const int bid = blockIdx.x;
    const int b = bid / C, c = bid % C;
    const size_t base = ((size_t)b * N_ + (size_t)c * R) * D_;
    const float4* kp = (const float4*)(kin + base);
    const float4* vp = (const float4*)(vin + base);

    __shared__ float lk[TI][D_];
    __shared__ float lv[TI][D_];

    const int tid = threadIdx.x;
    const int td = tid >> 4;
    const int te = tid & 15;

    float acc[4][4];
#pragma unroll
    for (int i = 0; i < 4; ++i)
#pragma unroll
        for (int j = 0; j < 4; ++j) acc[i][j] = 0.0f;

    const int ntiles = R / TI;
    for (int t = 0; t < ntiles; ++t) {
#pragma unroll
        for (int u = tid; u < TI * (D_ / 4); u += 256) {
            float4 kk = kp[t * TI * (D_ / 4) + u];
            float4 vv = vp[t * TI * (D_ / 4) + u];
            const int r = u >> 4, cc = (u & 15) * 4;
            float4 ek;
            ek.x = elu1(kk.x); ek.y = elu1(kk.y);
            ek.z = elu1(kk.z); ek.w = elu1(kk.w);
            *(float4*)&lk[r][cc] = ek;
            *(float4*)&lv[r][cc] = vv;
        }
        __syncthreads();
#pragma unroll 8
        for (int r = 0; r < TI; ++r) {
            const float4 kk = *(const float4*)&lk[r][td * 4];
            const float4 vv = *(const float4*)&lv[r][te * 4];
            const float kd[4] = {kk.x, kk.y, kk.z, kk.w};
            const float ve[4] = {vv.x, vv.y, vv.z, vv.w};
#pragma unroll
            for (int i = 0; i < 4; ++i)
#pragma unroll
                for (int j = 0; j < 4; ++j)
                    acc[i][j] = __fmaf_rn(kd[i], ve[j], acc[i][j]);
        }
        __syncthreads();
    }

    float* pb = kv + (size_t)b * (D_ * D_);
#pragma unroll
    for (int i = 0; i < 4; ++i)
#pragma unroll
        for (int j = 0; j < 4; ++j)
            atomicAdd(&pb[(4 * td + i) * D_ + 4 * te + j], acc[i][j]);
}

// ---------------------------------------------------------------------------
// Pass 1b: reduce C partials -> final KV written in-place to chunk 0.
// 4-way independent partial sums for load pipelining.
// ---------------------------------------------------------------------------
__global__ __launch_bounds__(256) void k2_reduce(float* __restrict__ part, int C) {
    const int i = blockIdx.x * 256 + threadIdx.x;  // 0 .. B_*4096-1
    const int b = i >> 12, jj = i & 4095;
    float* p = part + (size_t)b * C * (D_ * D_) + jj;
    float s0 = 0.0f, s1 = 0.0f, s2 = 0.0f, s3 = 0.0f;
    int c = 0;
    for (; c + 4 <= C; c += 4) {
        s0 += p[(size_t)(c + 0) * (D_ * D_)];
        s1 += p[(size_t)(c + 1) * (D_ * D_)];
        s2 += p[(size_t)(c + 2) * (D_ * D_)];
        s3 += p[(size_t)(c + 3) * (D_ * D_)];
    }
    for (; c < C; ++c) s0 += p[(size_t)c * (D_ * D_)];
    p[0] = (s0 + s1) + (s2 + s3);
}

// ---------------------------------------------------------------------------
// Pass 2 (v3): out[b,n,:] = phi(q[b,n,:]) @ KV[b] * (1/(D*N)).
// 2 rows per thread: thread (rp, j) handles rows {2rp, 2rp+1} of a 128-row
// tile and e-quads {4j+16s}. q loaded DIRECTLY from global per d-chunk
// (4 j-threads broadcast-share each row via L1; no shfl). KV in LDS, each
// b128 read amortized over 2 rows -> VALU:LDS ~ 64:48 cyc (v2 was 8:12,
// LDS-pipe-bound, plus 64 bpermutes/thread). Stores unchanged from v2
// (lane-unit-stride 16B -> full 64B sectors).
// ---------------------------------------------------------------------------
__global__ __launch_bounds__(256, 4) void k3_out(const float* __restrict__ q,
                                                 const float* __restrict__ kvbuf,
                                                 int kvstride,
                                                 float* __restrict__ out) {
    __shared__ float skv[D_ * D_];
    const int b = blockIdx.x >> 6;        // 64 blocks per batch (128 rows each)
    const int tile = blockIdx.x & 63;

    // stage KV coalesced
    const float4* kvg = (const float4*)(kvbuf + (size_t)b * kvstride);
    float4* skv4 = (float4*)skv;
#pragma unroll
    for (int u = 0; u < 4; ++u)
        skv4[threadIdx.x + 256 * u] = kvg[threadIdx.x + 256 * u];

    const int rp = threadIdx.x >> 2;      // 0..63 row-pair
    const int j = threadIdx.x & 3;
    const size_t row0 = (size_t)b * N_ + (size_t)tile * 128 + 2 * rp;
    const float* q0 = q + row0 * D_;
    const float* q1 = q0 + D_;

    __syncthreads();

    float4 acc0[4], acc1[4];
#pragma unroll
    for (int s = 0; s < 4; ++s) {
        acc0[s] = {0.0f, 0.0f, 0.0f, 0.0f};
        acc1[s] = {0.0f, 0.0f, 0.0f, 0.0f};
    }

    for (int d0 = 0; d0 < 4; ++d0) {
        // load q for d-range [16*d0, 16*d0+16) of both rows + elu
        float qa[16], qb[16];
#pragma unroll
        for (int u = 0; u < 4; ++u) {
            float4 ta = *(const float4*)(q0 + d0 * 16 + 4 * u);
            float4 tb = *(const float4*)(q1 + d0 * 16 + 4 * u);
            qa[4 * u + 0] = elu1(ta.x); qa[4 * u + 1] = elu1(ta.y);
            qa[4 * u + 2] = elu1(ta.z); qa[4 * u + 3] = elu1(ta.w);
            qb[4 * u + 0] = elu1(tb.x); qb[4 * u + 1] = elu1(tb.y);
            qb[4 * u + 2] = elu1(tb.z); qb[4 * u + 3] = elu1(tb.w);
        }
#pragma unroll
        for (int dd = 0; dd < 16; ++dd) {
            const int d = d0 * 16 + dd;
            const float qda = qa[dd];
            const float qdb = qb[dd];
#pragma unroll
            for (int s = 0; s < 4; ++s) {
                const float4 kvv = *(const float4*)&skv[d * D_ + s * 16 + j * 4];
                acc0[s].x = __fmaf_rn(qda, kvv.x, acc0[s].x);
                acc0[s].y = __fmaf_rn(qda, kvv.y, acc0[s].y);
                acc0[s].z = __fmaf_rn(qda, kvv.z, acc0[s].z);
                acc0[s].w = __fmaf_rn(qda, kvv.w, acc0[s].w);
                acc1[s].x = __fmaf_rn(qdb, kvv.x, acc1[s].x);
                acc1[s].y = __fmaf_rn(qdb, kvv.y, acc1[s].y);
                acc1[s].z = __fmaf_rn(qdb, kvv.z, acc1[s].z);
                acc1[s].w = __fmaf_rn(qdb, kvv.w, acc1[s].w);
            }
        }
    }

    const float scale = 1.0f / (float)((size_t)D_ * N_);
    float4* op0 = (float4*)(out + row0 * D_);
    float4* op1 = (float4*)(out + (row0 + 1) * D_);
#pragma unroll
    for (int s = 0; s < 4; ++s) {
        float4 o0 = {acc0[s].x * scale, acc0[s].y * scale,
                     acc0[s].z * scale, acc0[s].w * scale};
        float4 o1 = {acc1[s].x * scale, acc1[s].y * scale,
                     acc1[s].z * scale, acc1[s].w * scale};
        op0[4 * s + j] = o0;   // e-quad (4j+16s) -> float4 index 4s+j
        op1[4 * s + j] = o1;
    }
}

extern "C" void kernel_launch(void* const* d_in, const int* in_sizes, int n_in,
                              void* d_out, int out_size, void* d_ws, size_t ws_size,
                              hipStream_t stream) {
    const float* q = (const float*)d_in[0];
    const float* k = (const float*)d_in[1];
    const float* v = (const float*)d_in[2];
    float* out = (float*)d_out;
    float* ws = (float*)d_ws;

    const size_t mat = (size_t)D_ * D_;  // 4096 floats per KV matrix

    // pick largest chunk count whose partial buffer fits in ws (C=128 pref:
    // 2048 blocks -> 8 blocks/CU for k1 latency hiding)
    int C = 0;
    for (int cc = 128; cc >= 2; cc >>= 1) {
        if (ws_size >= (size_t)B_ * cc * mat * sizeof(float)) { C = cc; break; }
    }

    if (C >= 2) {
        const int R = N_ / C;
        k1_partial<<<B_ * C, 256, 0, stream>>>(k, v, ws, C, R);
        k2_reduce<<<(int)(B_ * mat) / 256, 256, 0, stream>>>(ws, C);
        k3_out<<<B_ * (N_ / 128), 256, 0, stream>>>(q, ws, (int)(C * mat), out);
    } else {
        // tiny-ws fallback: zero KV then atomically accumulate
        hipMemsetAsync(d_ws, 0, B_ * mat * sizeof(float), stream);
        const int C2 = 64, R = N_ / C2;
        k1_atomic<32><<<B_ * C2, 256, 0, stream>>>(k, v, ws, C2, R);
        k3_out<<<B_ * (N_ / 128), 256, 0, stream>>>(q, ws, (int)mat, out);
    }
}